// Round 1
// baseline (183.398 us; speedup 1.0000x reference)
//
#include <hip/hip_runtime.h>
#include <hip/hip_bf16.h>
#include <hip/hip_cooperative_groups.h>

#define B_ 2
#define L_ 2048
#define H_ 8
#define D_ 64
#define SP_ 65       // STRIDE+1
#define NC_ 128      // 16-row chunks per (b,h)
#define RS_ 512      // H_*D_ floats between consecutive seq rows

typedef __attribute__((ext_vector_type(8))) short bf16x8;
typedef __attribute__((ext_vector_type(16))) float f32x16;

static __device__ inline short f2bf(float x) {
    return __builtin_bit_cast(short, __float2bfloat16(x));
}

static __device__ inline bf16x8 ld8_bf16(const float* __restrict__ p) {
    float4 a = *(const float4*)p;
    float4 b = *(const float4*)(p + 4);
    bf16x8 r;
    r[0]=f2bf(a.x); r[1]=f2bf(a.y); r[2]=f2bf(a.z); r[3]=f2bf(a.w);
    r[4]=f2bf(b.x); r[5]=f2bf(b.y); r[6]=f2bf(b.z); r[7]=f2bf(b.w);
    return r;
}

static __device__ inline bf16x8 ones_frag() {
    bf16x8 r;
    short o = f2bf(1.f);
    #pragma unroll
    for (int t = 0; t < 8; ++t) r[t] = o;
    return r;
}

// ============ Fused cooperative kernel ============
// Phase A:
//   wib 0,1 : local 32-row tile x 64-col band, SINGLE wave (both col halves).
//             Result (32x64 f32 partial + z) parked in this wave's LDS region.
//   wib 2,3 : strided residue units (1040 total, <=2 per wave) -> pB/zB (HBM)
//             + 2 csum1 16-row V-chunk sums each.
// grid.sync()
// Phase B:
//   each wave finalizes 16 rows of the block's two tiles:
//   out = (pA_lds + pB + prefix(csum1)) / (zA_lds + zB + (i+1))
__global__ __launch_bounds__(256, 2) void fused_k(const float* __restrict__ q,
                                                  const float* __restrict__ kk,
                                                  const float* __restrict__ v,
                                                  float* __restrict__ csum1,
                                                  float* __restrict__ pB,
                                                  float* __restrict__ zB,
                                                  float* __restrict__ out) {
    __shared__ float LDS[8704];          // 4 waves x 2176 floats
    int wib  = threadIdx.x >> 6;
    int lane = threadIdx.x & 63;
    int half = lane >> 5, ln = lane & 31;
    float* Pw = LDS + wib * 2176;

    if (wib < 2) {
        // ---------- local tile, single wave: rows T..T+31, band cols T-16..T+47
        int team = blockIdx.x * 2 + wib;     // 0..1023
        int bh = team >> 6;
        int T  = (team & 63) << 5;
        int h = bh & 7, b = bh >> 3;
        const size_t base = (size_t)b * L_ * RS_ + (size_t)h * D_;

        // V prefetch: 64 band rows, dims ln and 32+ln
        bf16x8 bv0[4], bv1[4];
        #pragma unroll
        for (int kb = 0; kb < 4; ++kb) {
            #pragma unroll
            for (int jj = 0; jj < 8; ++jj) {
                int jr = T - 16 + kb * 16 + half * 8 + jj;
                jr = jr < 0 ? 0 : (jr > L_ - 1 ? L_ - 1 : jr);
                const float* vr = v + base + (size_t)jr * RS_;
                bv0[kb][jj] = f2bf(vr[ln]);
                bv1[kb][jj] = f2bf(vr[32 + ln]);
            }
        }

        // Q fragments (rows T+ln)
        const float* qrow = q + base + (size_t)(T + ln) * RS_;
        bf16x8 aq[4];
        #pragma unroll
        for (int kb = 0; kb < 4; ++kb) aq[kb] = ld8_bf16(qrow + kb * 16 + half * 8);

        // QK^T + weights for both 32-col tiles
        #pragma unroll
        for (int ct = 0; ct < 2; ++ct) {
            int j = T - 16 + 32 * ct + ln;
            j = j < 0 ? 0 : (j > L_ - 1 ? L_ - 1 : j);
            const float* krow = kk + base + (size_t)j * RS_;
            f32x16 acc = {};
            #pragma unroll
            for (int kb = 0; kb < 4; ++kb) {
                bf16x8 kf = ld8_bf16(krow + kb * 16 + half * 8);
                acc = __builtin_amdgcn_mfma_f32_32x32x16_bf16(aq[kb], kf, acc, 0, 0, 0);
            }
            #pragma unroll
            for (int r = 0; r < 16; ++r) {
                int m = (r & 3) + 8 * (r >> 2) + 4 * half;
                float w;
                if (ct == 0) {
                    bool act = (ln >= m) && (ln <= m + 16) && (T - 16 + ln >= 0);
                    w = act ? (__expf(0.125f * acc[r]) - 1.f) : 0.f;
                    if ((m < 16) && (ln >= 16) && (ln <= m + 16)) w += 1.f;
                } else {
                    bool act = (ln <= m - 16);
                    w = act ? (__expf(0.125f * acc[r]) - 1.f) : 0.f;
                    if ((m >= 16) && (ln <= m - 16)) w += 1.f;
                }
                Pw[m * 68 + 32 * ct + ln] = w;
            }
        }
        // same-wave ds_write -> ds_read: compiler inserts lgkmcnt; no barrier needed

        // PV over full 64-col band, both dim halves + denominator
        f32x16 p0 = {}; f32x16 p1 = {}; f32x16 po = {};
        bf16x8 ones = ones_frag();
        #pragma unroll
        for (int kb = 0; kb < 4; ++kb) {
            const float* pr = &Pw[ln * 68 + kb * 16 + half * 8];
            float4 x = *(const float4*)pr;
            float4 y = *(const float4*)(pr + 4);
            bf16x8 ap;
            ap[0]=f2bf(x.x); ap[1]=f2bf(x.y); ap[2]=f2bf(x.z); ap[3]=f2bf(x.w);
            ap[4]=f2bf(y.x); ap[5]=f2bf(y.y); ap[6]=f2bf(y.z); ap[7]=f2bf(y.w);
            p0 = __builtin_amdgcn_mfma_f32_32x32x16_bf16(ap, bv0[kb], p0, 0, 0, 0);
            p1 = __builtin_amdgcn_mfma_f32_32x32x16_bf16(ap, bv1[kb], p1, 0, 0, 0);
            po = __builtin_amdgcn_mfma_f32_32x32x16_bf16(ap, ones,    po, 0, 0, 0);
        }

        // park local partials in LDS (pA never touches HBM)
        #pragma unroll
        for (int r = 0; r < 16; ++r) {
            int m = (r & 3) + 8 * (r >> 2) + 4 * half;
            Pw[m * 68 + ln]      = p0[r];
            Pw[m * 68 + 32 + ln] = p1[r];
            if (ln == 0) Pw[m * 68 + 64] = po[r];
        }
    } else {
        // ---------- strided residue units + csum1 chunks
        int sw = blockIdx.x * 2 + (wib - 2);   // 0..1023
        #pragma unroll 1
        for (int rep = 0; rep < 2; ++rep) {
            if (rep == 1 && sw >= 16) break;
            int us = (rep == 0) ? sw : 1024 + sw;   // 0..1039
            int bh = us / SP_;
            int r  = us % SP_;
            int h = bh & 7, b = bh >> 3;
            const size_t base = (size_t)b * L_ * RS_ + (size_t)h * D_;

            bf16x8 bv0[2], bv1[2];
            #pragma unroll
            for (int kb = 0; kb < 2; ++kb) {
                int k0 = kb * 16 + half * 8;
                #pragma unroll
                for (int jj = 0; jj < 8; ++jj) {
                    int lv = r + SP_ * (k0 + jj);
                    lv = lv > L_ - 1 ? L_ - 1 : lv;
                    const float* vr = v + base + (size_t)lv * RS_;
                    bv0[kb][jj] = f2bf(vr[ln]);
                    bv1[kb][jj] = f2bf(vr[32 + ln]);
                }
            }

            int lq = r + SP_ * ln;
            int lqc = lq > L_ - 1 ? L_ - 1 : lq;
            const float* qrow = q  + base + (size_t)lqc * RS_;
            const float* krow = kk + base + (size_t)lqc * RS_;
            f32x16 acc = {};
            #pragma unroll
            for (int kb = 0; kb < 4; ++kb) {
                bf16x8 a  = ld8_bf16(qrow + kb * 16 + half * 8);
                bf16x8 bb = ld8_bf16(krow + kb * 16 + half * 8);
                acc = __builtin_amdgcn_mfma_f32_32x32x16_bf16(a, bb, acc, 0, 0, 0);
            }
            #pragma unroll
            for (int rg = 0; rg < 16; ++rg) {
                int m = (rg & 3) + 8 * (rg >> 2) + 4 * half;
                bool act = (ln < m) && (r + SP_ * m < L_);
                Pw[m * 36 + ln] = act ? (__expf(0.125f * acc[rg]) - 1.f) : 0.f;
            }

            f32x16 p0 = {}; f32x16 p1 = {}; f32x16 po = {};
            bf16x8 ones = ones_frag();
            #pragma unroll
            for (int kb = 0; kb < 2; ++kb) {
                const float* pr = &Pw[ln * 36 + kb * 16 + half * 8];
                float4 x = *(const float4*)pr;
                float4 y = *(const float4*)(pr + 4);
                bf16x8 ap;
                ap[0]=f2bf(x.x); ap[1]=f2bf(x.y); ap[2]=f2bf(x.z); ap[3]=f2bf(x.w);
                ap[4]=f2bf(y.x); ap[5]=f2bf(y.y); ap[6]=f2bf(y.z); ap[7]=f2bf(y.w);
                p0 = __builtin_amdgcn_mfma_f32_32x32x16_bf16(ap, bv0[kb], p0, 0, 0, 0);
                p1 = __builtin_amdgcn_mfma_f32_32x32x16_bf16(ap, bv1[kb], p1, 0, 0, 0);
                po = __builtin_amdgcn_mfma_f32_32x32x16_bf16(ap, ones,    po, 0, 0, 0);
            }
            float* pBr = pB + (size_t)bh * L_ * D_;
            float* zBr = zB + (size_t)bh * L_;
            #pragma unroll
            for (int rg = 0; rg < 16; ++rg) {
                int m = (rg & 3) + 8 * (rg >> 2) + 4 * half;
                int l = r + SP_ * m;
                if (l < L_) {
                    pBr[(size_t)l * D_ + ln]      = p0[rg];
                    pBr[(size_t)l * D_ + 32 + ln] = p1[rg];
                    if (ln == 0) zBr[l] = po[rg];
                }
            }
        }

        // csum1: two 16-row V-chunk sums per wave
        #pragma unroll 1
        for (int t = 0; t < 2; ++t) {
            int uc = sw * 2 + t;             // 0..2047 = bh*128 + c
            int c  = uc & (NC_ - 1);
            int bh = uc >> 7;
            int h = bh & 7, b = bh >> 3;
            const float* vb = v + (size_t)(b * L_ + c * 16) * RS_ + h * D_ + lane;
            float s = 0.f;
            #pragma unroll
            for (int l = 0; l < 16; ++l) s += vb[l * RS_];
            csum1[(size_t)uc * D_ + lane] = s;
        }
    }

    cooperative_groups::this_grid().sync();

    // ---------- Phase B: finalize. Wave handles 16 rows of tile (blockIdx*2 + wib&1).
    {
        int team = blockIdx.x * 2 + (wib & 1);
        int m0   = (wib >> 1) << 4;          // 0 or 16
        int bh = team >> 6;
        int T  = (team & 63) << 5;
        int h = bh & 7, b = bh >> 3;
        const float* PL = LDS + (wib & 1) * 2176;
        const float* zBr = zB + (size_t)bh * L_;

        // z prefetch (starts divide chain inputs early)
        float zrow[16];
        #pragma unroll
        for (int rr = 0; rr < 16; ++rr) zrow[rr] = zBr[T + m0 + rr];

        // prefix over csum1: chunks c < cEnd (L2/L3-hot, 4-way unrolled)
        int cEnd = (T >> 4) + (m0 ? 1 : 0);
        const float* cs = csum1 + (size_t)bh * NC_ * D_ + lane;
        float s0 = 0.f, s1 = 0.f, s2 = 0.f, s3 = 0.f;
        int c = 0;
        for (; c + 4 <= cEnd; c += 4) {
            s0 += cs[(c + 0) * D_]; s1 += cs[(c + 1) * D_];
            s2 += cs[(c + 2) * D_]; s3 += cs[(c + 3) * D_];
        }
        for (; c < cEnd; ++c) s0 += cs[c * D_];
        float pr = (s0 + s1) + (s2 + s3);

        const float* pBr = pB + (size_t)bh * L_ * D_;
        const size_t obase = (size_t)b * L_ * RS_ + (size_t)h * D_;
        #pragma unroll
        for (int rr = 0; rr < 16; ++rr) {
            int m = m0 + rr;
            int i = T + m;
            float zs  = PL[m * 68 + 64] - (float)((m & 15) + 1) + zrow[rr] + (float)(i + 1);
            float num = PL[m * 68 + lane] + pBr[(size_t)i * D_ + lane] + pr;
            out[obase + (size_t)i * RS_ + lane] = num / zs;
        }
    }
}

extern "C" void kernel_launch(void* const* d_in, const int* in_sizes, int n_in,
                              void* d_out, int out_size, void* d_ws, size_t ws_size,
                              hipStream_t stream) {
    const float* q = (const float*)d_in[0];
    const float* k = (const float*)d_in[1];
    const float* v = (const float*)d_in[2];
    // d_in[3] = attn_mask: deterministic causal — not read.
    float* out = (float*)d_out;

    float* csum1 = (float*)d_ws;                          // 131072 f
    float* pB    = csum1 + (size_t)B_ * H_ * NC_ * D_;    // 2097152 f
    float* zB    = pB    + (size_t)B_ * H_ * L_ * D_;     // 32768 f

    void* args[] = {(void*)&q, (void*)&k, (void*)&v,
                    (void*)&csum1, (void*)&pB, (void*)&zB, (void*)&out};
    // 512 blocks = 2/CU co-resident (LDS 34.8KB, launch_bounds caps VGPR<=256)
    hipLaunchCooperativeKernel(fused_k, dim3(512), dim3(256), args, 0, stream);
}

// Round 2
// 161.922 us; speedup vs baseline: 1.1326x; 1.1326x over previous
//
#include <hip/hip_runtime.h>
#include <hip/hip_bf16.h>

#define B_ 2
#define L_ 2048
#define H_ 8
#define D_ 64
#define SP_ 65       // STRIDE+1
#define RS_ 512      // H_*D_ floats between consecutive seq rows

typedef __attribute__((ext_vector_type(8))) short bf16x8;
typedef __attribute__((ext_vector_type(4))) float f32x4;
typedef __attribute__((ext_vector_type(16))) float f32x16;

static __device__ inline short f2bf(float x) {
    return __builtin_bit_cast(short, __float2bfloat16(x));
}

static __device__ inline bf16x8 ld8_bf16(const float* __restrict__ p) {
    f32x4 a = *(const f32x4*)p;
    f32x4 b = *(const f32x4*)(p + 4);
    bf16x8 r;
    r[0]=f2bf(a[0]); r[1]=f2bf(a[1]); r[2]=f2bf(a[2]); r[3]=f2bf(a[3]);
    r[4]=f2bf(b[0]); r[5]=f2bf(b[1]); r[6]=f2bf(b[2]); r[7]=f2bf(b[3]);
    return r;
}

static __device__ inline bf16x8 ones_frag() {
    bf16x8 r;
    short o = f2bf(1.f);
    #pragma unroll
    for (int t = 0; t < 8; ++t) r[t] = o;
    return r;
}

// ================= Single fused kernel, plain launch ========================
// Block = 512 threads = 8 waves, handles a PAIR of 32-row tiles (T0 = 32*pi,
// T1 = 2016 - 32*pi, same bh) so strided work per block is constant (~992 pairs).
// waves 0-3: two 2-wave local-band teams (round-0-verified MFMA path),
//            partials parked in LDS; walk (ones-prefix of V) in region 1.
// waves 4-7: strided diagonal terms j = i-65k recomputed in f32 VALU
//            (dots lane=k, V-accum lane=dim), then finalize + out write.
// Grid 512 blocks -> 2 blocks/CU, all co-resident; no inter-block deps.
//
// LDS (floats): Pw0[32][68] @0, Pw1[32][68] @2176 (weights -> park; col64 = z)
//               WL[64][32] @4352 (strided w), WP[2][4][64] @6400 (walk partials)
//               EX[2][64] @6912 (16-row chunk T..T+16). total 7040 f = 28.2 KB
__global__ __launch_bounds__(512, 4) void dozer_k(const float* __restrict__ q,
                                                  const float* __restrict__ kk,
                                                  const float* __restrict__ v,
                                                  float* __restrict__ out) {
    __shared__ float LDS[7040];
    const int tid  = threadIdx.x;
    const int wib  = tid >> 6;
    const int lane = tid & 63;
    const int half = lane >> 5, ln = lane & 31;

    const int bh = blockIdx.x >> 5;
    const int pi = blockIdx.x & 31;
    const int T0 = pi << 5;
    const int T1 = 2016 - (pi << 5);
    const int h = bh & 7, b = bh >> 3;
    const size_t base = (size_t)b * L_ * RS_ + (size_t)h * D_;

    float* WL = LDS + 4352;
    float* WP = LDS + 6400;
    float* EX = LDS + 6912;

    // persistent per-path state across barriers
    bf16x8 bv0[4];
    f32x16 pL = {}; f32x16 po = {};
    int tile = 0, hf = 0, T = 0, d0 = 0;
    float* Pw = LDS;
    float num[16], den[16];

    // ---------------- Region 0 ----------------
    if (wib < 4) {
        tile = wib >> 1; hf = wib & 1; T = tile ? T1 : T0; d0 = hf << 5;
        Pw = LDS + tile * 2176;
        // V prefetch: band rows, this wave's dims [d0, d0+32)
        #pragma unroll
        for (int kb = 0; kb < 4; ++kb) {
            #pragma unroll
            for (int jj = 0; jj < 8; ++jj) {
                int jr = T - 16 + kb * 16 + half * 8 + jj;
                jr = jr < 0 ? 0 : (jr > L_ - 1 ? L_ - 1 : jr);
                bv0[kb][jj] = f2bf(v[base + (size_t)jr * RS_ + d0 + ln]);
            }
        }
        // Q fragments (rows T+ln)
        const float* qrow = q + base + (size_t)(T + ln) * RS_;
        bf16x8 aq[4];
        #pragma unroll
        for (int kb = 0; kb < 4; ++kb) aq[kb] = ld8_bf16(qrow + kb * 16 + half * 8);
        // QK^T for this wave's 32-col tile (cols T-16+d0 .. +31)
        int j = T - 16 + d0 + ln;
        j = j < 0 ? 0 : (j > L_ - 1 ? L_ - 1 : j);
        const float* krow = kk + base + (size_t)j * RS_;
        f32x16 acc = {};
        #pragma unroll
        for (int kb = 0; kb < 4; ++kb) {
            bf16x8 kf = ld8_bf16(krow + kb * 16 + half * 8);
            acc = __builtin_amdgcn_mfma_f32_32x32x16_bf16(aq[kb], kf, acc, 0, 0, 0);
        }
        // weights (exp-1 masked + "+1" prefix fold) into this wave's col half
        #pragma unroll
        for (int r = 0; r < 16; ++r) {
            int m = (r & 3) + 8 * (r >> 2) + 4 * half;
            float w;
            if (hf == 0) {
                bool act = (ln >= m) && (ln <= m + 16) && (T - 16 + ln >= 0);
                w = act ? (__expf(0.125f * acc[r]) - 1.f) : 0.f;
                if ((m < 16) && (ln >= 16) && (ln <= m + 16)) w += 1.f;
            } else {
                bool act = (ln <= m - 16);
                w = act ? (__expf(0.125f * acc[r]) - 1.f) : 0.f;
                if ((m >= 16) && (ln <= m - 16)) w += 1.f;
            }
            Pw[m * 68 + d0 + ln] = w;
        }
    } else {
        // strided dots: 16 rows/wave, 2 rows per pass (one per half), lane=k
        const int s = wib - 4;
        #pragma unroll
        for (int u = 0; u < 8; ++u) {
            int grh = s + ((u * 2 + half) << 2);     // row id 0..63
            int tl = grh >> 5, m = grh & 31;
            int i = (tl ? T1 : T0) + m;
            int K = i / SP_;                          // # strided cols below band
            bool act = ln < K;                        // this lane's k = ln+1
            int jj = i - SP_ * (ln + 1);
            jj = act ? jj : 0;
            const float* qr = q  + base + (size_t)i  * RS_;
            const float* kr = kk + base + (size_t)jj * RS_;
            f32x4 a4 = {0.f, 0.f, 0.f, 0.f};
            #pragma unroll
            for (int c = 0; c < 16; ++c) {
                f32x4 qa = *(const f32x4*)(qr + 4 * c);
                f32x4 ka = *(const f32x4*)(kr + 4 * c);
                a4 += qa * ka;
            }
            float dot = (a4[0] + a4[1]) + (a4[2] + a4[3]);
            if (act) WL[grh * 32 + ln + 1] = __expf(0.125f * dot) - 1.f;
        }
    }

    __syncthreads();   // bar1: weights visible to team partner; WL complete

    // ---------------- Region 1 ----------------
    if (wib < 4) {
        // PV over full 64-col band, this wave's 32 output dims (+ po on hf==1)
        bf16x8 ones = ones_frag();
        #pragma unroll
        for (int kb = 0; kb < 4; ++kb) {
            const float* pr = &Pw[ln * 68 + kb * 16 + half * 8];
            f32x4 x = *(const f32x4*)pr;
            f32x4 y = *(const f32x4*)(pr + 4);
            bf16x8 ap;
            ap[0]=f2bf(x[0]); ap[1]=f2bf(x[1]); ap[2]=f2bf(x[2]); ap[3]=f2bf(x[3]);
            ap[4]=f2bf(y[0]); ap[5]=f2bf(y[1]); ap[6]=f2bf(y[2]); ap[7]=f2bf(y[3]);
            pL = __builtin_amdgcn_mfma_f32_32x32x16_bf16(ap, bv0[kb], pL, 0, 0, 0);
            if (hf == 1)
                po = __builtin_amdgcn_mfma_f32_32x32x16_bf16(ap, ones, po, 0, 0, 0);
        }
        // walk: ones-prefix sums of V rows [0,T) for both tiles, 4-way split
        {
            int c4 = (lane & 15) << 2, rp = lane >> 4;   // 4 rows per f32x4 pass
            const float* vb = v + base + c4;
            f32x4 w0 = {0.f,0.f,0.f,0.f}, w1 = {0.f,0.f,0.f,0.f};
            int n0 = T0 >> 4, n1 = T1 >> 4;
            for (int qi = 0; qi < n0; ++qi) {
                int jr = 16 * qi + 4 * wib + rp;
                w0 += *(const f32x4*)(vb + (size_t)jr * RS_);
            }
            for (int qi = 0; qi < n1; ++qi) {
                int jr = 16 * qi + 4 * wib + rp;
                w1 += *(const f32x4*)(vb + (size_t)jr * RS_);
            }
            #pragma unroll
            for (int t = 0; t < 4; ++t) {
                w0[t] += __shfl_xor(w0[t], 16);
                w1[t] += __shfl_xor(w1[t], 16);
            }
            #pragma unroll
            for (int t = 0; t < 4; ++t) {
                w0[t] += __shfl_xor(w0[t], 32);
                w1[t] += __shfl_xor(w1[t], 32);
            }
            if (lane < 16) {
                *(f32x4*)&WP[(0 * 4 + wib) * 64 + c4] = w0;
                *(f32x4*)&WP[(1 * 4 + wib) * 64 + c4] = w1;
            }
        }
    } else {
        // strided V-accumulation (lane=dim), num/den per owned row
        const int s = wib - 4;
        #pragma unroll
        for (int p = 0; p < 16; ++p) {
            int gr = s + 4 * p;
            int tl = gr >> 5, m = gr & 31;
            int i = (tl ? T1 : T0) + m;
            int K = i / SP_;
            float nu = 0.f, de = 0.f;
            const float* vp = v + base + lane;
            int k = 1;
            for (; k + 3 <= K; k += 4) {
                float wa = WL[gr * 32 + k];
                float wb = WL[gr * 32 + k + 1];
                float wc = WL[gr * 32 + k + 2];
                float wd = WL[gr * 32 + k + 3];
                nu = fmaf(wa, vp[(size_t)(i - SP_ * k)       * RS_], nu);
                nu = fmaf(wb, vp[(size_t)(i - SP_ * (k + 1)) * RS_], nu);
                nu = fmaf(wc, vp[(size_t)(i - SP_ * (k + 2)) * RS_], nu);
                nu = fmaf(wd, vp[(size_t)(i - SP_ * (k + 3)) * RS_], nu);
                de += (wa + wb) + (wc + wd);
            }
            for (; k <= K; ++k) {
                float w = WL[gr * 32 + k];
                nu = fmaf(w, vp[(size_t)(i - SP_ * k) * RS_], nu);
                de += w;
            }
            num[p] = nu; den[p] = de;
        }
        // 16-row chunk sums V[T..T+16) (needed for rows m>=16)
        if (s < 2) {
            int Tt = s ? T1 : T0;
            float e = 0.f;
            #pragma unroll
            for (int r = 0; r < 16; ++r) e += v[base + (size_t)(Tt + r) * RS_ + lane];
            EX[s * 64 + lane] = e;
        }
    }

    __syncthreads();   // bar2: PV's LDS reads complete -> safe to overwrite Pw

    // ---------------- Region 2: park local partials ----------------
    if (wib < 4) {
        #pragma unroll
        for (int r = 0; r < 16; ++r) {
            int m = (r & 3) + 8 * (r >> 2) + 4 * half;
            Pw[m * 68 + d0 + ln] = pL[r];
            if (hf == 1 && ln == 0)
                Pw[m * 68 + 64] = po[r] - (float)((m & 15) + 1);
        }
    }

    __syncthreads();   // bar3: parks + walk partials + EX visible

    // ---------------- Region 3: finalize (strided waves) ----------------
    if (wib >= 4) {
        const int s = wib - 4;
        float S0  = WP[0*64 + lane] + WP[1*64 + lane] + WP[2*64 + lane] + WP[3*64 + lane];
        float S1  = WP[4*64 + lane] + WP[5*64 + lane] + WP[6*64 + lane] + WP[7*64 + lane];
        float S0e = S0 + EX[lane];
        float S1e = S1 + EX[64 + lane];
        #pragma unroll
        for (int p = 0; p < 16; ++p) {
            int gr = s + 4 * p;
            int tl = gr >> 5, m = gr & 31;
            int i = (tl ? T1 : T0) + m;
            const float* Pt = LDS + tl * 2176;
            float pl = Pt[m * 68 + lane];
            float z  = Pt[m * 68 + 64];
            float pref = tl ? (m < 16 ? S1 : S1e) : (m < 16 ? S0 : S0e);
            float numv = pl + num[p] + pref;
            float denv = z + den[p] + (float)(i + 1);
            out[base + (size_t)i * RS_ + lane] = numv / denv;
        }
    }
}

extern "C" void kernel_launch(void* const* d_in, const int* in_sizes, int n_in,
                              void* d_out, int out_size, void* d_ws, size_t ws_size,
                              hipStream_t stream) {
    const float* q = (const float*)d_in[0];
    const float* k = (const float*)d_in[1];
    const float* v = (const float*)d_in[2];
    // d_in[3] = attn_mask: deterministic causal — not read.
    float* out = (float*)d_out;
    (void)d_ws; (void)ws_size;   // no workspace: all partials live in LDS/regs

    // 512 blocks x 512 threads: 16 bh x 32 tile-pairs (T, 2016-T) — constant
    // per-block strided work, 2 blocks/CU all co-resident, plain launch
    // (graph-capture friendly).
    dozer_k<<<512, 512, 0, stream>>>(q, k, v, out);
}

// Round 3
// 108.898 us; speedup vs baseline: 1.6841x; 1.4869x over previous
//
#include <hip/hip_runtime.h>
#include <hip/hip_bf16.h>

#define B_ 2
#define L_ 2048
#define H_ 8
#define D_ 64
#define SP_ 65       // STRIDE+1
#define NC_ 128      // level-1 chunks (16 rows each)
#define NH_ 16       // level-2 chunks (128 rows each)
#define RS_ 512      // H_*D_ floats between consecutive seq rows

typedef __attribute__((ext_vector_type(8))) short bf16x8;
typedef __attribute__((ext_vector_type(16))) float f32x16;

static __device__ inline short f2bf(float x) {
    return __builtin_bit_cast(short, __float2bfloat16(x));
}

static __device__ inline bf16x8 ld8_bf16(const float* __restrict__ p) {
    float4 a = *(const float4*)p;
    float4 b = *(const float4*)(p + 4);
    bf16x8 r;
    r[0]=f2bf(a.x); r[1]=f2bf(a.y); r[2]=f2bf(a.z); r[3]=f2bf(a.w);
    r[4]=f2bf(b.x); r[5]=f2bf(b.y); r[6]=f2bf(b.z); r[7]=f2bf(b.w);
    return r;
}

static __device__ inline bf16x8 ones_frag() {
    bf16x8 r;
    short o = f2bf(1.f);
    #pragma unroll
    for (int t = 0; t < 8; ++t) r[t] = o;
    return r;
}

// ================= Kernel 1: ALL input-only partials, one launch ============
// blk <  512 : local 32-row tiles, 2-wave teams (2 teams/block; 1024 tiles)
// blk <  772 : strided residue units (4 waves/block, 1040 units)
// blk < 1284 : csum1 16-row V sums (4 waves/block, 2048 units)
// blk < 1348 : csumH 128-row V sums (4 waves/block, 256 units)
__global__ __launch_bounds__(256) void partials_k(const float* __restrict__ q,
                                                  const float* __restrict__ kk,
                                                  const float* __restrict__ v,
                                                  float* __restrict__ csum1,
                                                  float* __restrict__ pA,
                                                  float* __restrict__ zA,
                                                  float* __restrict__ pB,
                                                  float* __restrict__ zB,
                                                  float* __restrict__ csumH) {
    __shared__ float LDS[4608];          // local: 2 teams x 32x68; strided: 4 x 32x36
    int wib  = threadIdx.x >> 6;
    int lane = threadIdx.x & 63;
    int half = lane >> 5, ln = lane & 31;
    int blk  = blockIdx.x;

    if (blk < 512) {
        // ---------- local tile, 2-wave team: wave hf = col-tile hf, dims [32hf,32hf+32)
        int tb = wib >> 1;
        int hf = wib & 1;
        int team = blk * 2 + tb;         // 0..1023
        int bh = team >> 6;
        int T  = (team & 63) << 5;
        int h = bh & 7, b = bh >> 3;
        const size_t base = (size_t)b * L_ * RS_ + (size_t)h * D_;
        float* Pw = LDS + tb * 2176;     // [32][68]
        int d0 = 32 * hf;

        // V prefetch: band rows, this wave's dims [d0, d0+32)
        bf16x8 bv[4];
        #pragma unroll
        for (int kb = 0; kb < 4; ++kb) {
            #pragma unroll
            for (int jj = 0; jj < 8; ++jj) {
                int jr = T - 16 + kb * 16 + half * 8 + jj;
                jr = jr < 0 ? 0 : (jr > L_ - 1 ? L_ - 1 : jr);
                bv[kb][jj] = f2bf(v[base + (size_t)jr * RS_ + d0 + ln]);
            }
        }

        // QK^T for this wave's 32-col tile
        const float* qrow = q + base + (size_t)(T + ln) * RS_;
        bf16x8 aq[4];
        #pragma unroll
        for (int kb = 0; kb < 4; ++kb) aq[kb] = ld8_bf16(qrow + kb * 16 + half * 8);

        int j = T - 16 + d0 + ln;
        j = j < 0 ? 0 : (j > L_ - 1 ? L_ - 1 : j);
        const float* krow = kk + base + (size_t)j * RS_;
        f32x16 acc = {};
        #pragma unroll
        for (int kb = 0; kb < 4; ++kb) {
            bf16x8 kf = ld8_bf16(krow + kb * 16 + half * 8);
            acc = __builtin_amdgcn_mfma_f32_32x32x16_bf16(aq[kb], kf, acc, 0, 0, 0);
        }

        // weights (exp-1 masked + "+1" prefix fold) into this wave's col half
        #pragma unroll
        for (int r = 0; r < 16; ++r) {
            int m = (r & 3) + 8 * (r >> 2) + 4 * half;
            float w;
            if (hf == 0) {
                bool act = (ln >= m) && (ln <= m + 16) && (T - 16 + ln >= 0);
                w = act ? (__expf(0.125f * acc[r]) - 1.f) : 0.f;
                if ((m < 16) && (ln >= 16) && (ln <= m + 16)) w += 1.f;
            } else {
                bool act = (ln <= m - 16);
                w = act ? (__expf(0.125f * acc[r]) - 1.f) : 0.f;
                if ((m >= 16) && (ln <= m - 16)) w += 1.f;
            }
            Pw[m * 68 + d0 + ln] = w;
        }
        __syncthreads();

        // PV over full 64-col band, this wave's 32 output dims (+ po on hf==1)
        f32x16 p = {}; f32x16 po = {};
        bf16x8 ones = ones_frag();
        #pragma unroll
        for (int kb = 0; kb < 4; ++kb) {
            int k0 = kb * 16 + half * 8;
            const float* pr = &Pw[ln * 68 + k0];
            float4 x = *(const float4*)pr;
            float4 y = *(const float4*)(pr + 4);
            bf16x8 ap;
            ap[0]=f2bf(x.x); ap[1]=f2bf(x.y); ap[2]=f2bf(x.z); ap[3]=f2bf(x.w);
            ap[4]=f2bf(y.x); ap[5]=f2bf(y.y); ap[6]=f2bf(y.z); ap[7]=f2bf(y.w);
            p = __builtin_amdgcn_mfma_f32_32x32x16_bf16(ap, bv[kb], p, 0, 0, 0);
            if (hf == 1)
                po = __builtin_amdgcn_mfma_f32_32x32x16_bf16(ap, ones, po, 0, 0, 0);
        }

        float* pAr = pA + (size_t)bh * L_ * D_;
        float* zAr = zA + (size_t)bh * L_;
        #pragma unroll
        for (int r = 0; r < 16; ++r) {
            int m = (r & 3) + 8 * (r >> 2) + 4 * half;
            int i = T + m;
            pAr[(size_t)i * D_ + d0 + ln] = p[r];
            if (hf == 1 && ln == 0)
                zAr[i] = po[r] - (float)((m & 15) + 1);
        }
    } else if (blk < 772) {
        // ---------- strided residue class mod 65: rows l = r + 65*s, s=0..31
        int us = (blk - 512) * 4 + wib;  // 0..1039
        int bh = us / SP_;
        int r  = us % SP_;
        int h = bh & 7, b = bh >> 3;
        const size_t base = (size_t)b * L_ * RS_ + (size_t)h * D_;
        float* Pw = LDS + wib * 1152;    // [32][36]

        bf16x8 bv0[2], bv1[2];
        #pragma unroll
        for (int kb = 0; kb < 2; ++kb) {
            int k0 = kb * 16 + half * 8;
            #pragma unroll
            for (int jj = 0; jj < 8; ++jj) {
                int lv = r + SP_ * (k0 + jj);
                lv = lv > L_ - 1 ? L_ - 1 : lv;
                const float* vr = v + base + (size_t)lv * RS_;
                bv0[kb][jj] = f2bf(vr[ln]);
                bv1[kb][jj] = f2bf(vr[32 + ln]);
            }
        }

        int lq = r + SP_ * ln;
        int lqc = lq > L_ - 1 ? L_ - 1 : lq;
        const float* qrow = q  + base + (size_t)lqc * RS_;
        const float* krow = kk + base + (size_t)lqc * RS_;
        f32x16 acc = {};
        #pragma unroll
        for (int kb = 0; kb < 4; ++kb) {
            bf16x8 a  = ld8_bf16(qrow + kb * 16 + half * 8);
            bf16x8 bb = ld8_bf16(krow + kb * 16 + half * 8);
            acc = __builtin_amdgcn_mfma_f32_32x32x16_bf16(a, bb, acc, 0, 0, 0);
        }
        #pragma unroll
        for (int rg = 0; rg < 16; ++rg) {
            int m = (rg & 3) + 8 * (rg >> 2) + 4 * half;
            bool act = (ln < m) && (r + SP_ * m < L_);
            Pw[m * 36 + ln] = act ? (__expf(0.125f * acc[rg]) - 1.f) : 0.f;
        }
        __syncthreads();

        f32x16 p0 = {}; f32x16 p1 = {}; f32x16 po = {};
        bf16x8 ones = ones_frag();
        #pragma unroll
        for (int kb = 0; kb < 2; ++kb) {
            int k0 = kb * 16 + half * 8;
            const float* pr = &Pw[ln * 36 + k0];
            float4 x = *(const float4*)pr;
            float4 y = *(const float4*)(pr + 4);
            bf16x8 ap;
            ap[0]=f2bf(x.x); ap[1]=f2bf(x.y); ap[2]=f2bf(x.z); ap[3]=f2bf(x.w);
            ap[4]=f2bf(y.x); ap[5]=f2bf(y.y); ap[6]=f2bf(y.z); ap[7]=f2bf(y.w);
            p0 = __builtin_amdgcn_mfma_f32_32x32x16_bf16(ap, bv0[kb], p0, 0, 0, 0);
            p1 = __builtin_amdgcn_mfma_f32_32x32x16_bf16(ap, bv1[kb], p1, 0, 0, 0);
            po = __builtin_amdgcn_mfma_f32_32x32x16_bf16(ap, ones,    po, 0, 0, 0);
        }
        float* pBr = pB + (size_t)bh * L_ * D_;
        float* zBr = zB + (size_t)bh * L_;
        #pragma unroll
        for (int rg = 0; rg < 16; ++rg) {
            int m = (rg & 3) + 8 * (rg >> 2) + 4 * half;
            int l = r + SP_ * m;
            if (l < L_) {
                pBr[(size_t)l * D_ + ln]      = p0[rg];
                pBr[(size_t)l * D_ + 32 + ln] = p1[rg];
                if (ln == 0) zBr[l] = po[rg];
            }
        }
    } else if (blk < 1284) {
        // ---------- csum1: 16-row chunk sums of V
        int uc = (blk - 772) * 4 + wib;  // 0..2047 = bh*128 + c
        int c = uc & (NC_ - 1);
        int bh = uc >> 7;
        int h = bh & 7, b = bh >> 3;
        const float* vb = v + (size_t)(b * L_ + c * 16) * RS_ + h * D_ + lane;
        float s = 0.f;
        #pragma unroll
        for (int l = 0; l < 16; ++l) s += vb[l * RS_];
        csum1[(size_t)uc * D_ + lane] = s;
    } else {
        // ---------- csumH: 128-row chunk sums of V (hierarchical prefix level 2)
        int uc = (blk - 1284) * 4 + wib; // 0..255 = bh*16 + cH
        int cH = uc & (NH_ - 1);
        int bh = uc >> 4;
        int h = bh & 7, b = bh >> 3;
        const float* vb = v + (size_t)(b * L_ + cH * 128) * RS_ + h * D_ + lane;
        float s0 = 0.f, s1 = 0.f, s2 = 0.f, s3 = 0.f;
        #pragma unroll 4
        for (int l = 0; l < 128; l += 4) {
            s0 += vb[(l + 0) * RS_]; s1 += vb[(l + 1) * RS_];
            s2 += vb[(l + 2) * RS_]; s3 += vb[(l + 3) * RS_];
        }
        csumH[(size_t)uc * D_ + lane] = (s0 + s1) + (s2 + s3);
    }
}

// ================= Kernel 2: combine + hierarchical prefix + divide =========
// One wave per 8-row group (4096 waves, 1024 blocks). Lane = dim.
// Prefix walk: <=15 csumH (128-row) loads + <=7 csum1 (16-row) loads
// (was <=127 csum1 loads in the flat version).
__global__ __launch_bounds__(256) void combine_k(const float* __restrict__ csum1,
                                                 const float* __restrict__ csumH,
                                                 const float* __restrict__ pA,
                                                 const float* __restrict__ zA,
                                                 const float* __restrict__ pB,
                                                 const float* __restrict__ zB,
                                                 float* __restrict__ out) {
    int wib  = threadIdx.x >> 6;
    int lane = threadIdx.x & 63;
    int u = blockIdx.x * 4 + wib;        // 0..4095
    int bh = u >> 8;
    int g  = u & 255;                    // 8-row group
    int i0 = g << 3;
    int c1 = i0 >> 4;                    // full 16-row chunks below this group
    int h = bh & 7, b = bh >> 3;

    const float* zAr = zA + (size_t)bh * L_;
    const float* zBr = zB + (size_t)bh * L_;
    // z prefetch first (starts the reciprocal chain early)
    float zsum[8];
    #pragma unroll
    for (int r = 0; r < 8; ++r) {
        int i = i0 + r;
        zsum[r] = zAr[i] + zBr[i] + (float)(i + 1);
    }

    // hierarchical prefix: nH 128-row blocks + nR 16-row chunks (L2-hot)
    int nH = c1 >> 3;                    // 0..15
    int nR = c1 & 7;                     // 0..7
    const float* csH = csumH + (size_t)bh * NH_ * D_ + lane;
    const float* cs1 = csum1 + ((size_t)bh * NC_ + (c1 & ~7)) * D_ + lane;
    float s0 = 0.f, s1 = 0.f, s2 = 0.f, s3 = 0.f;
    int cc = 0;
    for (; cc + 4 <= nH; cc += 4) {
        s0 += csH[(cc + 0) * D_]; s1 += csH[(cc + 1) * D_];
        s2 += csH[(cc + 2) * D_]; s3 += csH[(cc + 3) * D_];
    }
    for (; cc < nH; ++cc) s0 += csH[cc * D_];
    for (int t = 0; t < nR; ++t) {
        if (t & 1) s1 += cs1[t * D_]; else s2 += cs1[t * D_];
    }
    float pr = (s0 + s1) + (s2 + s3);

    const float* pAr = pA + (size_t)bh * L_ * D_;
    const float* pBr = pB + (size_t)bh * L_ * D_;
    const size_t obase = (size_t)b * L_ * RS_ + (size_t)h * D_;

    #pragma unroll
    for (int r = 0; r < 8; ++r) {
        int i = i0 + r;
        float num = pAr[(size_t)i * D_ + lane] + pBr[(size_t)i * D_ + lane] + pr;
        out[obase + (size_t)i * RS_ + lane] = num / zsum[r];
    }
}

extern "C" void kernel_launch(void* const* d_in, const int* in_sizes, int n_in,
                              void* d_out, int out_size, void* d_ws, size_t ws_size,
                              hipStream_t stream) {
    const float* q = (const float*)d_in[0];
    const float* k = (const float*)d_in[1];
    const float* v = (const float*)d_in[2];
    // d_in[3] = attn_mask: deterministic causal — not read.
    float* out = (float*)d_out;

    float* csum1 = (float*)d_ws;                          // 131072 f
    float* pA    = csum1 + (size_t)B_ * H_ * NC_ * D_;    // 2097152 f
    float* zA    = pA    + (size_t)B_ * H_ * L_ * D_;     // 32768 f
    float* pB    = zA    + (size_t)B_ * H_ * L_;          // 2097152 f
    float* zB    = pB    + (size_t)B_ * H_ * L_ * D_;     // 32768 f
    float* csumH = zB    + (size_t)B_ * H_ * L_;          // 16384 f

    // 512 local-team + 260 strided + 512 csum1 + 64 csumH blocks
    partials_k<<<1348, 256, 0, stream>>>(q, k, v, csum1, pA, zA, pB, zB, csumH);
    // combine: 4096 8-row groups, 4 waves/block
    combine_k<<<1024, 256, 0, stream>>>(csum1, csumH, pA, zA, pB, zB, out);
}

// Round 4
// 107.701 us; speedup vs baseline: 1.7028x; 1.0111x over previous
//
#include <hip/hip_runtime.h>
#include <hip/hip_bf16.h>

#define B_ 2
#define L_ 2048
#define H_ 8
#define D_ 64
#define SP_ 65       // STRIDE+1
#define NC_ 128      // level-1 chunks (16 rows each)
#define NH_ 16       // level-2 chunks (128 rows each)
#define RS_ 512      // H_*D_ floats between consecutive seq rows

typedef __attribute__((ext_vector_type(8))) short bf16x8;
typedef __attribute__((ext_vector_type(16))) float f32x16;

static __device__ inline short f2bf(float x) {
    return __builtin_bit_cast(short, __float2bfloat16(x));
}

static __device__ inline bf16x8 ld8_bf16(const float* __restrict__ p) {
    float4 a = *(const float4*)p;
    float4 b = *(const float4*)(p + 4);
    bf16x8 r;
    r[0]=f2bf(a.x); r[1]=f2bf(a.y); r[2]=f2bf(a.z); r[3]=f2bf(a.w);
    r[4]=f2bf(b.x); r[5]=f2bf(b.y); r[6]=f2bf(b.z); r[7]=f2bf(b.w);
    return r;
}

static __device__ inline bf16x8 ones_frag() {
    bf16x8 r;
    short o = f2bf(1.f);
    #pragma unroll
    for (int t = 0; t < 8; ++t) r[t] = o;
    return r;
}

// ================= Launch A: strided residue units + fused csum =============
// blk < 260 : strided residue units (4 waves/block, 1040 units) -> pB, zB
// blk < 324 : fused csum units (4 waves/block, 256 units): each 128-row unit
//             writes its 8 csum1 chunks AND csumH (single V pass).
__global__ __launch_bounds__(256) void pre_k(const float* __restrict__ q,
                                             const float* __restrict__ kk,
                                             const float* __restrict__ v,
                                             float* __restrict__ csum1,
                                             float* __restrict__ csumH,
                                             float* __restrict__ pB,
                                             float* __restrict__ zB) {
    __shared__ float LDS[4608];          // strided: 4 x 32x36
    int wib  = threadIdx.x >> 6;
    int lane = threadIdx.x & 63;
    int half = lane >> 5, ln = lane & 31;
    int blk  = blockIdx.x;

    if (blk < 260) {
        // ---------- strided residue class mod 65: rows l = r + 65*s, s=0..31
        int us = blk * 4 + wib;          // 0..1039
        int bh = us / SP_;
        int r  = us % SP_;
        int h = bh & 7, b = bh >> 3;
        const size_t base = (size_t)b * L_ * RS_ + (size_t)h * D_;
        float* Pw = LDS + wib * 1152;    // [32][36]

        bf16x8 bv0[2], bv1[2];
        #pragma unroll
        for (int kb = 0; kb < 2; ++kb) {
            int k0 = kb * 16 + half * 8;
            #pragma unroll
            for (int jj = 0; jj < 8; ++jj) {
                int lv = r + SP_ * (k0 + jj);
                lv = lv > L_ - 1 ? L_ - 1 : lv;
                const float* vr = v + base + (size_t)lv * RS_;
                bv0[kb][jj] = f2bf(vr[ln]);
                bv1[kb][jj] = f2bf(vr[32 + ln]);
            }
        }

        int lq = r + SP_ * ln;
        int lqc = lq > L_ - 1 ? L_ - 1 : lq;
        const float* qrow = q  + base + (size_t)lqc * RS_;
        const float* krow = kk + base + (size_t)lqc * RS_;
        f32x16 acc = {};
        #pragma unroll
        for (int kb = 0; kb < 4; ++kb) {
            bf16x8 a  = ld8_bf16(qrow + kb * 16 + half * 8);
            bf16x8 bb = ld8_bf16(krow + kb * 16 + half * 8);
            acc = __builtin_amdgcn_mfma_f32_32x32x16_bf16(a, bb, acc, 0, 0, 0);
        }
        #pragma unroll
        for (int rg = 0; rg < 16; ++rg) {
            int m = (rg & 3) + 8 * (rg >> 2) + 4 * half;
            bool act = (ln < m) && (r + SP_ * m < L_);
            Pw[m * 36 + ln] = act ? (__expf(0.125f * acc[rg]) - 1.f) : 0.f;
        }
        __syncthreads();

        f32x16 p0 = {}; f32x16 p1 = {}; f32x16 po = {};
        bf16x8 ones = ones_frag();
        #pragma unroll
        for (int kb = 0; kb < 2; ++kb) {
            int k0 = kb * 16 + half * 8;
            const float* pr = &Pw[ln * 36 + k0];
            float4 x = *(const float4*)pr;
            float4 y = *(const float4*)(pr + 4);
            bf16x8 ap;
            ap[0]=f2bf(x.x); ap[1]=f2bf(x.y); ap[2]=f2bf(x.z); ap[3]=f2bf(x.w);
            ap[4]=f2bf(y.x); ap[5]=f2bf(y.y); ap[6]=f2bf(y.z); ap[7]=f2bf(y.w);
            p0 = __builtin_amdgcn_mfma_f32_32x32x16_bf16(ap, bv0[kb], p0, 0, 0, 0);
            p1 = __builtin_amdgcn_mfma_f32_32x32x16_bf16(ap, bv1[kb], p1, 0, 0, 0);
            po = __builtin_amdgcn_mfma_f32_32x32x16_bf16(ap, ones,    po, 0, 0, 0);
        }
        float* pBr = pB + (size_t)bh * L_ * D_;
        float* zBr = zB + (size_t)bh * L_;
        #pragma unroll
        for (int rg = 0; rg < 16; ++rg) {
            int m = (rg & 3) + 8 * (rg >> 2) + 4 * half;
            int l = r + SP_ * m;
            if (l < L_) {
                pBr[(size_t)l * D_ + ln]      = p0[rg];
                pBr[(size_t)l * D_ + 32 + ln] = p1[rg];
                if (ln == 0) zBr[l] = po[rg];
            }
        }
    } else {
        // ---------- fused csum: one 128-row unit writes 8 csum1 + 1 csumH
        int uc = (blk - 260) * 4 + wib;  // 0..255 = bh*16 + cH
        int cH = uc & (NH_ - 1);
        int bh = uc >> 4;
        int h = bh & 7, b = bh >> 3;
        const float* vb = v + (size_t)(b * L_ + cH * 128) * RS_ + h * D_ + lane;
        float* c1p = csum1 + ((size_t)bh * NC_ + cH * 8) * D_ + lane;
        float hs = 0.f;
        #pragma unroll
        for (int c = 0; c < 8; ++c) {
            float s0 = 0.f, s1 = 0.f, s2 = 0.f, s3 = 0.f;
            #pragma unroll
            for (int l = 0; l < 16; l += 4) {
                s0 += vb[(c * 16 + l + 0) * RS_]; s1 += vb[(c * 16 + l + 1) * RS_];
                s2 += vb[(c * 16 + l + 2) * RS_]; s3 += vb[(c * 16 + l + 3) * RS_];
            }
            float s = (s0 + s1) + (s2 + s3);
            c1p[c * D_] = s;
            hs += s;
        }
        csumH[((size_t)bh * NH_ + cH) * D_ + lane] = hs;
    }
}

// ================= Launch B: local band MFMA + in-register finalize =========
// 512 blocks x 2 teams: team = local 32-row tile. After the band MFMA, the
// team finalizes its own rows (prefix from csum1/csumH, pB/zB from launch A)
// and writes out directly. pA/zA and the combine kernel are eliminated.
__global__ __launch_bounds__(256) void local_k(const float* __restrict__ q,
                                               const float* __restrict__ kk,
                                               const float* __restrict__ v,
                                               const float* __restrict__ csum1,
                                               const float* __restrict__ csumH,
                                               const float* __restrict__ pB,
                                               const float* __restrict__ zB,
                                               float* __restrict__ out) {
    __shared__ float LDS[4672];          // Pw 2x[32][68] @0; PF 2x[2][64] @4352; ZW 2x[32] @4608
    int wib  = threadIdx.x >> 6;
    int lane = threadIdx.x & 63;
    int half = lane >> 5, ln = lane & 31;
    // XCD-chunked swizzle (512 = 8 XCDs x 64): contiguous tiles per XCD ->
    // overlapping K/V bands hit the same L2.
    int wid = (blockIdx.x & 7) * 64 + (blockIdx.x >> 3);

    int tb = wib >> 1;
    int hf = wib & 1;
    int team = wid * 2 + tb;             // 0..1023
    int bh = team >> 6;
    int T  = (team & 63) << 5;
    int h = bh & 7, b = bh >> 3;
    const size_t base = (size_t)b * L_ * RS_ + (size_t)h * D_;
    float* Pw = LDS + tb * 2176;         // [32][68]
    float* PF = LDS + 4352 + tb * 128;   // [2][64]: P0, P1
    float* ZW = LDS + 4608 + tb * 32;    // [32]: band z per row
    int d0 = 32 * hf;

    // V prefetch: band rows, this wave's dims [d0, d0+32)
    bf16x8 bv[4];
    #pragma unroll
    for (int kb = 0; kb < 4; ++kb) {
        #pragma unroll
        for (int jj = 0; jj < 8; ++jj) {
            int jr = T - 16 + kb * 16 + half * 8 + jj;
            jr = jr < 0 ? 0 : (jr > L_ - 1 ? L_ - 1 : jr);
            bv[kb][jj] = f2bf(v[base + (size_t)jr * RS_ + d0 + ln]);
        }
    }

    // QK^T for this wave's 32-col tile
    const float* qrow = q + base + (size_t)(T + ln) * RS_;
    bf16x8 aq[4];
    #pragma unroll
    for (int kb = 0; kb < 4; ++kb) aq[kb] = ld8_bf16(qrow + kb * 16 + half * 8);

    int j = T - 16 + d0 + ln;
    j = j < 0 ? 0 : (j > L_ - 1 ? L_ - 1 : j);
    const float* krow = kk + base + (size_t)j * RS_;
    f32x16 acc = {};
    #pragma unroll
    for (int kb = 0; kb < 4; ++kb) {
        bf16x8 kf = ld8_bf16(krow + kb * 16 + half * 8);
        acc = __builtin_amdgcn_mfma_f32_32x32x16_bf16(aq[kb], kf, acc, 0, 0, 0);
    }

    // weights (exp-1 masked + "+1" prefix fold) into this wave's col half
    #pragma unroll
    for (int r = 0; r < 16; ++r) {
        int m = (r & 3) + 8 * (r >> 2) + 4 * half;
        float w;
        if (hf == 0) {
            bool act = (ln >= m) && (ln <= m + 16) && (T - 16 + ln >= 0);
            w = act ? (__expf(0.125f * acc[r]) - 1.f) : 0.f;
            if ((m < 16) && (ln >= 16) && (ln <= m + 16)) w += 1.f;
        } else {
            bool act = (ln <= m - 16);
            w = act ? (__expf(0.125f * acc[r]) - 1.f) : 0.f;
            if ((m >= 16) && (ln <= m - 16)) w += 1.f;
        }
        Pw[m * 68 + d0 + ln] = w;
    }

    // hf==0 wave: hierarchical prefix for this tile (2 values x 64 dims)
    if (hf == 0) {
        int c1 = T >> 4;                 // 16-row chunks below T (0..126)
        int nH = c1 >> 3, nR = c1 & 7;
        const float* csH = csumH + (size_t)bh * NH_ * D_ + lane;
        const float* cs1 = csum1 + ((size_t)bh * NC_ + (c1 & ~7)) * D_ + lane;
        float s0 = 0.f, s1 = 0.f, s2 = 0.f, s3 = 0.f;
        int cc = 0;
        for (; cc + 4 <= nH; cc += 4) {
            s0 += csH[(cc + 0) * D_]; s1 += csH[(cc + 1) * D_];
            s2 += csH[(cc + 2) * D_]; s3 += csH[(cc + 3) * D_];
        }
        for (; cc < nH; ++cc) s0 += csH[cc * D_];
        for (int t = 0; t < nR; ++t) {
            if (t & 1) s1 += cs1[t * D_]; else s2 += cs1[t * D_];
        }
        float P0 = (s0 + s1) + (s2 + s3);
        float P1 = P0 + csum1[((size_t)bh * NC_ + c1) * D_ + lane];
        PF[lane]      = P0;
        PF[64 + lane] = P1;
    }
    __syncthreads();

    // prefetch pB/zB for this wave's rows (L3-hot from launch A) — issued
    // before PV so the loads overlap the MFMA chain.
    const float* pBr = pB + (size_t)bh * L_ * D_;
    const float* zBr = zB + (size_t)bh * L_;
    float pbv[16], zbv[16];
    #pragma unroll
    for (int r = 0; r < 16; ++r) {
        int m = (r & 3) + 8 * (r >> 2) + 4 * half;
        int i = T + m;
        pbv[r] = pBr[(size_t)i * D_ + d0 + ln];
        zbv[r] = zBr[i];
    }

    // PV over full 64-col band, this wave's 32 output dims (+ po on hf==1)
    f32x16 p = {}; f32x16 po = {};
    bf16x8 ones = ones_frag();
    #pragma unroll
    for (int kb = 0; kb < 4; ++kb) {
        int k0 = kb * 16 + half * 8;
        const float* pr = &Pw[ln * 68 + k0];
        float4 x = *(const float4*)pr;
        float4 y = *(const float4*)(pr + 4);
        bf16x8 ap;
        ap[0]=f2bf(x.x); ap[1]=f2bf(x.y); ap[2]=f2bf(x.z); ap[3]=f2bf(x.w);
        ap[4]=f2bf(y.x); ap[5]=f2bf(y.y); ap[6]=f2bf(y.z); ap[7]=f2bf(y.w);
        p = __builtin_amdgcn_mfma_f32_32x32x16_bf16(ap, bv[kb], p, 0, 0, 0);
        if (hf == 1)
            po = __builtin_amdgcn_mfma_f32_32x32x16_bf16(ap, ones, po, 0, 0, 0);
    }

    // hf==1 publishes the band denominator per row
    if (hf == 1) {
        #pragma unroll
        for (int r = 0; r < 16; ++r) {
            int m = (r & 3) + 8 * (r >> 2) + 4 * half;
            if (ln == 0) ZW[m] = po[r] - (float)((m & 15) + 1);
        }
    }
    __syncthreads();

    // finalize: out = (band + strided + prefix) / z, straight from registers
    float Pf0 = PF[d0 + ln];
    float Pf1 = PF[64 + d0 + ln];
    #pragma unroll
    for (int r = 0; r < 16; ++r) {
        int m = (r & 3) + 8 * (r >> 2) + 4 * half;
        int i = T + m;
        float z   = ZW[m] + zbv[r] + (float)(i + 1);
        float num = p[r] + pbv[r] + (m < 16 ? Pf0 : Pf1);
        out[base + (size_t)i * RS_ + d0 + ln] = num / z;
    }
}

extern "C" void kernel_launch(void* const* d_in, const int* in_sizes, int n_in,
                              void* d_out, int out_size, void* d_ws, size_t ws_size,
                              hipStream_t stream) {
    const float* q = (const float*)d_in[0];
    const float* k = (const float*)d_in[1];
    const float* v = (const float*)d_in[2];
    // d_in[3] = attn_mask: deterministic causal — not read.
    float* out = (float*)d_out;

    float* csum1 = (float*)d_ws;                          // 131072 f
    float* pB    = csum1 + (size_t)B_ * H_ * NC_ * D_;    // 2097152 f
    float* zB    = pB    + (size_t)B_ * H_ * L_ * D_;     // 32768 f
    float* csumH = zB    + (size_t)B_ * H_ * L_;          // 16384 f

    // Launch A: 260 strided + 64 fused-csum blocks
    pre_k<<<324, 256, 0, stream>>>(q, k, v, csum1, csumH, pB, zB);
    // Launch B: 512 blocks (1024 local tiles), finalize fused
    local_k<<<512, 256, 0, stream>>>(q, k, v, csum1, csumH, pB, zB, out);
}